// Round 1
// baseline (60.432 us; speedup 1.0000x reference)
//
#include <hip/hip_runtime.h>
#include <hip/hip_bf16.h>
#include <math.h>

#define HWV (1080 * 1920)
#define NPIX (2 * HWV)

// ---------------------------------------------------------------------------
// Prep kernel: (a) transpose bilateral grid (n,c,z,y,x) -> (n,y,x,z,c) so the
// 12 channels at a corner are contiguous (3x float4 loads); (b) fold BN into
// the first conv's weights/bias. Runs once per launch, tiny.
// ---------------------------------------------------------------------------
__global__ void prep_kernel(const float* __restrict__ grid,
                            const float* __restrict__ w1,
                            const float* __restrict__ b1,
                            const float* __restrict__ gamma,
                            const float* __restrict__ beta,
                            const float* __restrict__ mean,
                            const float* __restrict__ var,
                            const float* __restrict__ w2,
                            const float* __restrict__ b2,
                            float* __restrict__ wsg,   // 49152 floats
                            float* __restrict__ wsw) { // 81+ floats
    int i = blockIdx.x * blockDim.x + threadIdx.x;
    if (i < 2 * 12 * 8 * 16 * 16) {
        // dst index i = (((n*16 + y)*16 + x)*8 + z)*12 + c
        int c = i % 12;
        int t = i / 12;
        int z = t % 8;  t /= 8;
        int x = t % 16; t /= 16;
        int y = t % 16;
        int n = t / 16;
        // src: grid[n][c][z][y][x], strides n:24576 c:2048 z:256 y:16 x:1
        wsg[i] = grid[n * 24576 + c * 2048 + z * 256 + y * 16 + x];
    }
    if (i < 16) {
        float inv = gamma[i] / sqrtf(var[i] + 1e-5f);
        wsw[i]      = w1[i * 3 + 0] * inv;               // wr
        wsw[16 + i] = w1[i * 3 + 1] * inv;               // wg
        wsw[32 + i] = w1[i * 3 + 2] * inv;               // wb
        wsw[48 + i] = (b1[i] - mean[i]) * inv + beta[i]; // folded bias
        wsw[64 + i] = w2[i];                             // second layer
    }
    if (i == 0) wsw[80] = b2[0];
}

// ---------------------------------------------------------------------------
// Fused kernel: guide MLP -> trilinear slice -> apply coeffs, 1 thread/pixel.
// ---------------------------------------------------------------------------
__global__ __launch_bounds__(256) void fused_kernel(
        const float* __restrict__ fullres,
        const float* __restrict__ wsg,
        const float* __restrict__ wsw,
        float* __restrict__ out) {
    __shared__ float sw[81];
    if (threadIdx.x < 81) sw[threadIdx.x] = wsw[threadIdx.x];
    __syncthreads();

    int i = blockIdx.x * 256 + threadIdx.x;
    if (i >= NPIX) return;
    int n = i / HWV;
    int p = i - n * HWV;
    int y = p / 1920;
    int x = p - y * 1920;

    const float* fr = fullres + n * 3 * HWV + p;
    float r = fr[0];
    float g = fr[HWV];
    float b = fr[2 * HWV];

    // ---- guide MLP (BN folded) ----
    float acc = sw[80];
#pragma unroll
    for (int c = 0; c < 16; ++c) {
        float t = fmaf(sw[c], r, fmaf(sw[16 + c], g, fmaf(sw[32 + c], b, sw[48 + c])));
        t = fmaxf(t, 0.0f);
        acc = fmaf(sw[64 + c], t, acc);
    }
    float guide = 1.0f / (1.0f + expf(-acc));

    // ---- interpolation coordinates ----
    float gz = guide * 7.0f;
    float z0f = floorf(gz);
    float tz = gz - z0f;
    int z0 = min((int)z0f, 7);       // gz >= 0
    int z1 = min(z0 + 1, 7);

    float gy = (float)y * (15.0f / 1079.0f);
    float y0f = floorf(gy);
    float ty = gy - y0f;
    int y0 = min((int)y0f, 15);
    int y1 = min(y0 + 1, 15);

    float gx = (float)x * (15.0f / 1919.0f);
    float x0f = floorf(gx);
    float tx = gx - x0f;
    int x0 = min((int)x0f, 15);
    int x1 = min(x0 + 1, 15);

    float wyv[2] = {1.0f - ty, ty};  int ysv[2] = {y0, y1};
    float wxv[2] = {1.0f - tx, tx};  int xsv[2] = {x0, x1};
    float wzv[2] = {1.0f - tz, tz};  int zsv[2] = {z0, z1};

    float co[12];
#pragma unroll
    for (int c = 0; c < 12; ++c) co[c] = 0.0f;

    const float* gbase = wsg + n * (16 * 16 * 8 * 12);
#pragma unroll
    for (int jy = 0; jy < 2; ++jy) {
#pragma unroll
        for (int jx = 0; jx < 2; ++jx) {
            float wxy = wyv[jy] * wxv[jx];
            const float* cb = gbase + (ysv[jy] * 16 + xsv[jx]) * 8 * 12;
#pragma unroll
            for (int jz = 0; jz < 2; ++jz) {
                float w = wxy * wzv[jz];
                const float4* p4 = (const float4*)(cb + zsv[jz] * 12);
                float4 a = p4[0];
                float4 d = p4[1];
                float4 e = p4[2];
                co[0] = fmaf(w, a.x, co[0]);
                co[1] = fmaf(w, a.y, co[1]);
                co[2] = fmaf(w, a.z, co[2]);
                co[3] = fmaf(w, a.w, co[3]);
                co[4] = fmaf(w, d.x, co[4]);
                co[5] = fmaf(w, d.y, co[5]);
                co[6] = fmaf(w, d.z, co[6]);
                co[7] = fmaf(w, d.w, co[7]);
                co[8] = fmaf(w, e.x, co[8]);
                co[9] = fmaf(w, e.y, co[9]);
                co[10] = fmaf(w, e.z, co[10]);
                co[11] = fmaf(w, e.w, co[11]);
            }
        }
    }

    // ---- apply coeffs ----
    float* op = out + n * 3 * HWV + p;
    op[0]       = fmaf(co[0], r, fmaf(co[1], g, fmaf(co[2],  b, co[3])));
    op[HWV]     = fmaf(co[4], r, fmaf(co[5], g, fmaf(co[6],  b, co[7])));
    op[2 * HWV] = fmaf(co[8], r, fmaf(co[9], g, fmaf(co[10], b, co[11])));
}

extern "C" void kernel_launch(void* const* d_in, const int* in_sizes, int n_in,
                              void* d_out, int out_size, void* d_ws, size_t ws_size,
                              hipStream_t stream) {
    const float* fullres = (const float*)d_in[0];
    const float* grid    = (const float*)d_in[1];
    const float* w1      = (const float*)d_in[2];
    const float* b1      = (const float*)d_in[3];
    const float* gamma   = (const float*)d_in[4];
    const float* beta    = (const float*)d_in[5];
    const float* mean    = (const float*)d_in[6];
    const float* var     = (const float*)d_in[7];
    const float* w2      = (const float*)d_in[8];
    const float* b2      = (const float*)d_in[9];
    float* out = (float*)d_out;

    float* wsg = (float*)d_ws;          // 49152 floats (transposed grid)
    float* wsw = wsg + 49152;           // 81 floats (folded weights)

    prep_kernel<<<192, 256, 0, stream>>>(grid, w1, b1, gamma, beta, mean, var,
                                         w2, b2, wsg, wsw);

    int blocks = (NPIX + 255) / 256;    // 16200 exactly
    fused_kernel<<<blocks, 256, 0, stream>>>(fullres, wsg, wsw, out);
}